// Round 5
// baseline (288.359 us; speedup 1.0000x reference)
//
#include <hip/hip_runtime.h>

typedef __attribute__((ext_vector_type(8))) _Float16 half8;
typedef __attribute__((ext_vector_type(8))) short short8;
typedef __attribute__((ext_vector_type(4))) float f32x4;
typedef unsigned short u16;

// ---------- fp16 helpers ----------
__device__ __forceinline__ u16 f2h(float x) {
    return __builtin_bit_cast(u16, (_Float16)x);   // RNE
}

// ---------- async global->LDS (16B/lane, linear dest: base + lane*16) ----------
__device__ __forceinline__ void g2l16(const u16* g, u16* l) {
    __builtin_amdgcn_global_load_lds(
        (const __attribute__((address_space(1))) void*)g,
        (__attribute__((address_space(3))) void*)l, 16, 0, 0);
}

// ---------- epilogue store dispatch ----------
__device__ __forceinline__ void storeC(float* C, size_t i, float v) { C[i] = v; }
__device__ __forceinline__ void storeC(u16* C, size_t i, float v)   { C[i] = f2h(v); }

// ---------- mask dtype detection (uint8 bool vs int32) ----------
__global__ void detect_mask_kernel(const unsigned char* __restrict__ m, int* __restrict__ flag) {
    __shared__ int any;
    if (threadIdx.x == 0) any = 0;
    __syncthreads();
    int base = threadIdx.x * 16;
    int local = 0;
#pragma unroll
    for (int j = 0; j < 16; ++j) {
        int idx = base + j;
        if ((idx & 3) != 0 && m[idx] != 0) local = 1;
    }
    if (local) atomicOr(&any, 1);
    __syncthreads();
    if (threadIdx.x == 0) flag[0] = any;
}

// ---------- cast fp32 -> f16 (+ optional copy into cat right half) ----------
__global__ __launch_bounds__(256) void cast_f16_kernel(
    const float* __restrict__ x, u16* __restrict__ dst,
    u16* __restrict__ cat_right, long n)
{
    long i = ((long)blockIdx.x * 256 + threadIdx.x) * 4;
    if (i >= n) return;
    const float4 v = *(const float4*)(x + i);
    ushort4 h = make_ushort4(f2h(v.x), f2h(v.y), f2h(v.z), f2h(v.w));
    *(ushort4*)(dst + i) = h;
    if (cat_right) {
        long row = i >> 10, col = i & 1023;     // D = 1024
        *(ushort4*)(cat_right + row * 2048 + col) = h;
    }
}

// ---------- fused enc cast+transpose: fp32 [b][2048][1024] -> f16 [k][d] AND f16 [d][k] ----------
__global__ __launch_bounds__(256) void cast_enc_kernel(
    const float* __restrict__ src, u16* __restrict__ enc16, u16* __restrict__ encT)
{
    __shared__ u16 tile[64][68];
    const int b  = blockIdx.z;
    const int k0 = blockIdx.x * 64;
    const int d0 = blockIdx.y * 64;
    const int t  = threadIdx.x;
    const int kr = t >> 4;            // 0..15
    const int dc = (t & 15) * 4;      // 0..60
#pragma unroll
    for (int i = 0; i < 4; ++i) {
        const int k = kr + i * 16;
        const size_t off = ((size_t)(b * 2048 + k0 + k)) * 1024 + d0 + dc;
        const float4 v = *(const float4*)(src + off);
        const u16 h0 = f2h(v.x), h1 = f2h(v.y), h2 = f2h(v.z), h3 = f2h(v.w);
        *(ushort4*)(enc16 + off) = make_ushort4(h0, h1, h2, h3);
        tile[k][dc] = h0; tile[k][dc + 1] = h1; tile[k][dc + 2] = h2; tile[k][dc + 3] = h3;
    }
    __syncthreads();
#pragma unroll
    for (int i = 0; i < 4; ++i) {
        const int d = kr + i * 16;
        ushort4 o = make_ushort4(tile[dc][d], tile[dc + 1][d], tile[dc + 2][d], tile[dc + 3][d]);
        *(ushort4*)(encT + ((size_t)(b * 1024 + d0 + d)) * 2048 + k0 + dc) = o;
    }
}

// ---------- 8-wave pipelined GEMM: C[M][N] = A[M][K] * B[N][K]^T (f16, k-contiguous) ----------
// BM=256, BN=128, BK=64. 8 waves (2 M x 4 N), per-wave output 128 x 32.
// T2: XOR chunk swizzle (conflict-free ds_read_b128, pre-swizzled global src).
// T4: counted vmcnt, depth-2 prefetch over a TRIPLE-buffered LDS ring:
//     iter t stages tile t+2 into buf (t+2)%3, then vmcnt(12) waits only tile t
//     (t+1's 6 + t+2's 6 loads stay in flight across the barrier).
// T5: setprio around MFMA quadrants. 2 barriers per K=64.
template<bool MASKED, typename CT>
__global__ __launch_bounds__(512, 2) void gemm8_kernel(
    const u16* __restrict__ A, int lda, long sAb,
    const u16* __restrict__ B, int ldb, long sBb,
    CT* __restrict__ C, int ldc, long sCb,
    const void* __restrict__ mask, const int* __restrict__ mflagp, long sMb,
    int K, int nmt, int nnt)
{
    constexpr int BM = 256, BN = 128, BK = 64;
    constexpr int WN  = BN / 4;          // 32
    constexpr int NF  = WN / 16;         // 2
    constexpr int NF2 = NF / 2;          // 1
    constexpr int AE  = BM * BK;         // 16384 elems (32KB)
    constexpr int BE  = BN * BK;         // 8192 elems (16KB)
    constexpr int ACALLS = 4;            // per-wave staging calls for A
    constexpr int BCALLS = 2;            // per-wave staging calls for B

    __shared__ u16 smem[3 * (AE + BE)];  // 144KB: triple-buffered A+B K-tiles

    const int t = threadIdx.x;
    const int lane = t & 63, wid = t >> 6;
    const int wr = wid >> 2, wc = wid & 3;
    const int lr = lane & 15, lh = lane >> 4;

    // T1: XCD swizzle (gridDim multiple of 8, bijective)
    const int bid = blockIdx.x;
    const int swz = (bid & 7) * ((int)gridDim.x >> 3) + (bid >> 3);
    const int per_b = nmt * nnt;
    const int b   = swz / per_b;
    const int rem = swz % per_b;
    const long row0 = (long)(rem / nnt) * BM;
    const long col0 = (long)(rem % nnt) * BN;

    A += (size_t)b * sAb;
    B += (size_t)b * sBb;
    C += (size_t)b * sCb;

    // staging: 8 rows per call per wave; source col-chunk pre-swizzled
    // (inverse of the read-side XOR; involution within the 8-chunk row)
    const int srow = lane >> 3;                       // 0..7
    const int scol = ((lane & 7) ^ (lane >> 3)) * 8;  // element offset in BK
    const u16* pa[ACALLS];
    const u16* pb[BCALLS];
#pragma unroll
    for (int c = 0; c < ACALLS; ++c)
        pa[c] = A + (size_t)(row0 + wid * 8 * ACALLS + c * 8 + srow) * lda + scol;
#pragma unroll
    for (int c = 0; c < BCALLS; ++c)
        pb[c] = B + (size_t)(col0 + wid * 8 * BCALLS + c * 8 + srow) * ldb + scol;

    f32x4 acc[8][NF] = {};

    // swizzled LDS chunk term for ds_read: ((ks*4+lh) ^ (lr&7)) * 8 elems
    const int ch0 = ((0 * 4 + lh) ^ (lr & 7)) * 8;
    const int ch1 = ((1 * 4 + lh) ^ (lr & 7)) * 8;

    const int NT = K / BK;   // >= 16 for all our shapes

    auto stage = [&](int tile, int buf) {
        const long ko = (long)tile * BK;
        u16* sAn = smem + buf * (AE + BE);
        u16* sBn = sAn + AE;
#pragma unroll
        for (int c = 0; c < ACALLS; ++c) g2l16(pa[c] + ko, sAn + wid * (ACALLS * 512) + c * 512);
#pragma unroll
        for (int c = 0; c < BCALLS; ++c) g2l16(pb[c] + ko, sBn + wid * (BCALLS * 512) + c * 512);
    };

    // prologue: tiles 0 and 1 into bufs 0 and 1 (NT >= 2 always here)
    stage(0, 0);
    stage(1, 1);

    int cb = 0, sb = 2;   // compute-buffer, stage-buffer (= (tt+2)%3)
    for (int tt = 0; tt < NT; ++tt) {
        if (tt + 2 < NT) stage(tt + 2, sb);

        // depth-2 counted wait: only tile tt must be resident
        if (tt + 2 < NT)      asm volatile("s_waitcnt vmcnt(12)" ::: "memory");
        else if (tt + 1 < NT) asm volatile("s_waitcnt vmcnt(6)"  ::: "memory");
        else                  asm volatile("s_waitcnt vmcnt(0)"  ::: "memory");
        __builtin_amdgcn_s_barrier();

        const u16* sAc = smem + cb * (AE + BE);
        const u16* sBc = sAc + AE;

        half8 Ar[4][2], Bq0[NF2][2], Bq1[NF2][2];

        auto ldA = [&](int mh) {
#pragma unroll
            for (int fi = 0; fi < 4; ++fi) {
                const int r = wr * 128 + (mh * 4 + fi) * 16 + lr;
                Ar[fi][0] = *(const half8*)&sAc[r * 64 + ch0];
                Ar[fi][1] = *(const half8*)&sAc[r * 64 + ch1];
            }
        };
        auto ldB = [&](half8 (&Br)[NF2][2], int nh) {
#pragma unroll
            for (int nj = 0; nj < NF2; ++nj) {
                const int r = wc * WN + (nh * NF2 + nj) * 16 + lr;
                Br[nj][0] = *(const half8*)&sBc[r * 64 + ch0];
                Br[nj][1] = *(const half8*)&sBc[r * 64 + ch1];
            }
        };
        auto quad = [&](half8 (&Br)[NF2][2], int mh, int nh) {
            __builtin_amdgcn_s_setprio(1);
#pragma unroll
            for (int fi = 0; fi < 4; ++fi)
#pragma unroll
                for (int nj = 0; nj < NF2; ++nj)
#pragma unroll
                    for (int ks = 0; ks < 2; ++ks)
                        acc[mh * 4 + fi][nh * NF2 + nj] =
                            __builtin_amdgcn_mfma_f32_16x16x32_f16(
                                Ar[fi][ks], Br[nj][ks], acc[mh * 4 + fi][nh * NF2 + nj], 0, 0, 0);
            __builtin_amdgcn_s_setprio(0);
        };

        ldA(0); ldB(Bq0, 0); quad(Bq0, 0, 0);
        ldB(Bq1, 1);         quad(Bq1, 0, 1);
        ldA(1);              quad(Bq1, 1, 1);
                             quad(Bq0, 1, 0);

        __builtin_amdgcn_s_barrier();
        cb = (cb == 2) ? 0 : cb + 1;
        sb = (sb == 2) ? 0 : sb + 1;
    }

    int mf = 0;
    if constexpr (MASKED) mf = *mflagp;   // 1 -> uint8 bool, 0 -> int32

    // epilogue: C/D mapping col = lane&15, row = (lane>>4)*4 + reg
#pragma unroll
    for (int f = 0; f < 8; ++f) {
        const long rb = row0 + wr * 128 + f * 16 + lh * 4;
#pragma unroll
        for (int n = 0; n < NF; ++n) {
            const long c = col0 + wc * WN + n * 16 + lr;
#pragma unroll
            for (int r = 0; r < 4; ++r) {
                float v = acc[f][n][r];
                const size_t idx = (size_t)(rb + r) * ldc + c;
                if constexpr (MASKED) {
                    const size_t midx = (size_t)b * sMb + idx;
                    const bool on = mf ? (((const unsigned char*)mask)[midx] != 0)
                                       : (((const int*)mask)[midx] != 0);
                    if (on) v = -__builtin_inff();
                }
                storeC(C, idx, v);
            }
        }
    }
}

// ---------- row softmax: scores fp32 [8192][2048] -> P f16 [8192][2048] ----------
__global__ __launch_bounds__(256) void softmax_kernel(const float* __restrict__ S,
                                                      u16* __restrict__ P)
{
    const long row = blockIdx.x;
    const int t = threadIdx.x;
    const int lane = t & 63, wid = t >> 6;
    const float* src = S + row * 2048;
    float4 a = *(const float4*)(src + t * 8);
    float4 b = *(const float4*)(src + t * 8 + 4);
    float v[8] = {a.x, a.y, a.z, a.w, b.x, b.y, b.z, b.w};

    float m = v[0];
#pragma unroll
    for (int i = 1; i < 8; ++i) m = fmaxf(m, v[i]);
#pragma unroll
    for (int off = 32; off; off >>= 1) m = fmaxf(m, __shfl_xor(m, off));
    __shared__ float redm[4];
    __shared__ float reds[4];
    if (lane == 0) redm[wid] = m;
    __syncthreads();
    m = fmaxf(fmaxf(redm[0], redm[1]), fmaxf(redm[2], redm[3]));

    float e[8], s = 0.f;
#pragma unroll
    for (int i = 0; i < 8; ++i) { e[i] = __expf(v[i] - m); s += e[i]; }
#pragma unroll
    for (int off = 32; off; off >>= 1) s += __shfl_xor(s, off);
    if (lane == 0) reds[wid] = s;
    __syncthreads();
    s = (reds[0] + reds[1]) + (reds[2] + reds[3]);
    const float inv = 1.0f / s;

    short8 o;
#pragma unroll
    for (int i = 0; i < 8; ++i) o[i] = (short)f2h(e[i] * inv);
    *(short8*)(P + row * 2048 + t * 8) = o;
}

// ---------- launch ----------
extern "C" void kernel_launch(void* const* d_in, const int* in_sizes, int n_in,
                              void* d_out, int out_size, void* d_ws, size_t ws_size,
                              hipStream_t stream)
{
    const float* dec  = (const float*)d_in[0];          // [16][512][1024]
    const float* enc  = (const float*)d_in[1];          // [16][2048][1024]
    const void*  mask = (const void*)d_in[2];           // [16][512][2048] bool or int32
    const float* W    = (const float*)d_in[3];          // [1024][2048]
    float* out        = (float*)d_out;                  // [16][512][1024]

    // workspace carve (total 289,406,976 B)
    char* ws = (char*)d_ws;
    u16*   dec16  = (u16*)ws;                 ws += 16777216;   // 8192x1024 f16
    u16*   enc16  = (u16*)ws;                 ws += 67108864;   // 16x2048x1024 f16
    u16*   encT   = (u16*)ws;                 ws += 67108864;   // 16x1024x2048 f16
    u16*   W16    = (u16*)ws;                 ws += 4194304;    // 1024x2048 f16
    float* scores = (float*)ws;               ws += 67108864;   // 8192x2048 fp32
    u16*   P      = (u16*)ws;                 ws += 33554432;   // 8192x2048 f16
    u16*   cat    = (u16*)ws;                 ws += 33554432;   // 8192x2048 f16
    if (ws_size < (size_t)289406976) return;

    int* mflag = (int*)P;   // written step 0, read step 2; P body written step 3

    // 0) detect mask dtype
    detect_mask_kernel<<<1, 256, 0, stream>>>((const unsigned char*)mask, mflag);

    // 1) casts
    cast_f16_kernel<<<8192, 256, 0, stream>>>(dec, dec16, cat + 1024, 8388608L);
    cast_enc_kernel<<<dim3(32, 16, 16), 256, 0, stream>>>(enc, enc16, encT);
    cast_f16_kernel<<<2048, 256, 0, stream>>>(W, W16, nullptr, 2097152L);

    // 2) scores = dec @ enc^T + mask  (256x128 tiles, 16b x 2mt x 16nt = 512 blocks)
    gemm8_kernel<true, float><<<512, 512, 0, stream>>>(
        dec16, 1024, 512L * 1024,
        enc16, 1024, 2048L * 1024,
        scores, 2048, 512L * 2048,
        mask, mflag, 512L * 2048,
        1024, 2, 16);

    // 3) softmax rows -> P (f16)
    softmax_kernel<<<8192, 256, 0, stream>>>(scores, P);

    // 4) context = P @ encT^T -> cat left half  (256x128 tiles, 16b x 2 x 8 = 256 blocks)
    gemm8_kernel<false, u16><<<256, 512, 0, stream>>>(
        P, 2048, 512L * 2048,
        encT, 2048, 1024L * 2048,
        cat, 2048, 512L * 2048,
        nullptr, nullptr, 0,
        2048, 2, 8);

    // 5) out = cat @ W^T -> fp32  (256x128 tiles, 32mt x 8nt = 256 blocks, batch-free)
    gemm8_kernel<false, float><<<256, 512, 0, stream>>>(
        cat, 2048, 0,
        W16, 2048, 0,
        out, 1024, 0,
        nullptr, nullptr, 0,
        2048, 32, 8);
}

// Round 6
// 229.562 us; speedup vs baseline: 1.2561x; 1.2561x over previous
//
#include <hip/hip_runtime.h>

typedef __attribute__((ext_vector_type(8))) _Float16 half8;
typedef __attribute__((ext_vector_type(8))) short short8;
typedef __attribute__((ext_vector_type(4))) float f32x4;
typedef unsigned short u16;

// ---------- fp16 helpers ----------
__device__ __forceinline__ u16 f2h(float x) {
    return __builtin_bit_cast(u16, (_Float16)x);   // RNE
}

// ---------- async global->LDS (16B/lane, linear dest: base + lane*16) ----------
__device__ __forceinline__ void g2l16(const u16* g, u16* l) {
    __builtin_amdgcn_global_load_lds(
        (const __attribute__((address_space(1))) void*)g,
        (__attribute__((address_space(3))) void*)l, 16, 0, 0);
}

// ---------- epilogue store dispatch ----------
__device__ __forceinline__ void storeC(float* C, size_t i, float v) { C[i] = v; }
__device__ __forceinline__ void storeC(u16* C, size_t i, float v)   { C[i] = f2h(v); }

// ---------- mask dtype detection (uint8 bool vs int32) ----------
__global__ void detect_mask_kernel(const unsigned char* __restrict__ m, int* __restrict__ flag) {
    __shared__ int any;
    if (threadIdx.x == 0) any = 0;
    __syncthreads();
    int base = threadIdx.x * 16;
    int local = 0;
#pragma unroll
    for (int j = 0; j < 16; ++j) {
        int idx = base + j;
        if ((idx & 3) != 0 && m[idx] != 0) local = 1;
    }
    if (local) atomicOr(&any, 1);
    __syncthreads();
    if (threadIdx.x == 0) flag[0] = any;
}

// ---------- cast fp32 -> f16 (+ optional copy into cat right half) ----------
__global__ __launch_bounds__(256) void cast_f16_kernel(
    const float* __restrict__ x, u16* __restrict__ dst,
    u16* __restrict__ cat_right, long n)
{
    long i = ((long)blockIdx.x * 256 + threadIdx.x) * 4;
    if (i >= n) return;
    const float4 v = *(const float4*)(x + i);
    ushort4 h = make_ushort4(f2h(v.x), f2h(v.y), f2h(v.z), f2h(v.w));
    *(ushort4*)(dst + i) = h;
    if (cat_right) {
        long row = i >> 10, col = i & 1023;     // D = 1024
        *(ushort4*)(cat_right + row * 2048 + col) = h;
    }
}

// ---------- fused enc cast+transpose: fp32 [b][2048][1024] -> f16 [k][d] AND f16 [d][k] ----------
__global__ __launch_bounds__(256) void cast_enc_kernel(
    const float* __restrict__ src, u16* __restrict__ enc16, u16* __restrict__ encT)
{
    __shared__ u16 tile[64][68];
    const int b  = blockIdx.z;
    const int k0 = blockIdx.x * 64;
    const int d0 = blockIdx.y * 64;
    const int t  = threadIdx.x;
    const int kr = t >> 4;            // 0..15
    const int dc = (t & 15) * 4;      // 0..60
#pragma unroll
    for (int i = 0; i < 4; ++i) {
        const int k = kr + i * 16;
        const size_t off = ((size_t)(b * 2048 + k0 + k)) * 1024 + d0 + dc;
        const float4 v = *(const float4*)(src + off);
        const u16 h0 = f2h(v.x), h1 = f2h(v.y), h2 = f2h(v.z), h3 = f2h(v.w);
        *(ushort4*)(enc16 + off) = make_ushort4(h0, h1, h2, h3);
        tile[k][dc] = h0; tile[k][dc + 1] = h1; tile[k][dc + 2] = h2; tile[k][dc + 3] = h3;
    }
    __syncthreads();
#pragma unroll
    for (int i = 0; i < 4; ++i) {
        const int d = kr + i * 16;
        ushort4 o = make_ushort4(tile[dc][d], tile[dc + 1][d], tile[dc + 2][d], tile[dc + 3][d]);
        *(ushort4*)(encT + ((size_t)(b * 1024 + d0 + d)) * 2048 + k0 + dc) = o;
    }
}

// ---------- 8-wave pipelined GEMM: C[M][N] = A[M][K] * B[N][K]^T (f16, k-contiguous) ----------
// BM=256, BN in {256,128}, BK=64. 8 waves (2 M x 4 N). R4-verified schedule:
// T2 XOR swizzle (0 bank conflicts), T4 depth-1 counted vmcnt over double buffer,
// T5 setprio, T1 XCD swizzle. No mask here (moved to softmax).
template<int BN, typename CT>
__global__ __launch_bounds__(512, 2) void gemm8_kernel(
    const u16* __restrict__ A, int lda, long sAb,
    const u16* __restrict__ B, int ldb, long sBb,
    CT* __restrict__ C, int ldc, long sCb,
    int K, int nmt, int nnt)
{
    constexpr int BM = 256, BK = 64;
    constexpr int WN  = BN / 4;          // 64 or 32
    constexpr int NF  = WN / 16;         // 4 or 2
    constexpr int NF2 = NF / 2;          // 2 or 1
    constexpr int AE  = BM * BK;         // 16384 elems
    constexpr int BE  = BN * BK;         // 16384 or 8192
    constexpr int ACALLS = 4;
    constexpr int BCALLS = BE / 4096;    // 4 or 2
    constexpr int CALLS  = ACALLS + BCALLS;

    __shared__ u16 smem[2 * (AE + BE)];  // double-buffered A+B K-tiles

    const int t = threadIdx.x;
    const int lane = t & 63, wid = t >> 6;
    const int wr = wid >> 2, wc = wid & 3;
    const int lr = lane & 15, lh = lane >> 4;

    // T1: XCD swizzle (gridDim multiple of 8, bijective)
    const int bid = blockIdx.x;
    const int swz = (bid & 7) * ((int)gridDim.x >> 3) + (bid >> 3);
    const int per_b = nmt * nnt;
    const int b   = swz / per_b;
    const int rem = swz % per_b;
    const long row0 = (long)(rem / nnt) * BM;
    const long col0 = (long)(rem % nnt) * BN;

    A += (size_t)b * sAb;
    B += (size_t)b * sBb;
    C += (size_t)b * sCb;

    // staging: source col-chunk pre-swizzled (inverse of read-side XOR; involution)
    const int srow = lane >> 3;                       // 0..7
    const int scol = ((lane & 7) ^ (lane >> 3)) * 8;  // element offset in BK
    const u16* pa[ACALLS];
    const u16* pb[BCALLS];
#pragma unroll
    for (int c = 0; c < ACALLS; ++c)
        pa[c] = A + (size_t)(row0 + wid * 8 * ACALLS + c * 8 + srow) * lda + scol;
#pragma unroll
    for (int c = 0; c < BCALLS; ++c)
        pb[c] = B + (size_t)(col0 + wid * 8 * BCALLS + c * 8 + srow) * ldb + scol;

    f32x4 acc[8][NF] = {};

    // swizzled LDS chunk term for ds_read: ((ks*4+lh) ^ (lr&7)) * 8 elems
    const int ch0 = ((0 * 4 + lh) ^ (lr & 7)) * 8;
    const int ch1 = ((1 * 4 + lh) ^ (lr & 7)) * 8;

    const int NT = K / BK;

    // prologue: stage tile 0 into buf 0
    {
        u16* sAn = smem;
        u16* sBn = smem + AE;
#pragma unroll
        for (int c = 0; c < ACALLS; ++c) g2l16(pa[c], sAn + wid * (ACALLS * 512) + c * 512);
#pragma unroll
        for (int c = 0; c < BCALLS; ++c) g2l16(pb[c], sBn + wid * (BCALLS * 512) + c * 512);
    }

    int cur = 0;
    for (int tt = 0; tt < NT; ++tt) {
        if (tt + 1 < NT) {
            const long ko = (long)(tt + 1) * BK;
            u16* sAn = smem + (cur ^ 1) * (AE + BE);
            u16* sBn = sAn + AE;
#pragma unroll
            for (int c = 0; c < ACALLS; ++c) g2l16(pa[c] + ko, sAn + wid * (ACALLS * 512) + c * 512);
#pragma unroll
            for (int c = 0; c < BCALLS; ++c) g2l16(pb[c] + ko, sBn + wid * (BCALLS * 512) + c * 512);
            if constexpr (CALLS == 8) asm volatile("s_waitcnt vmcnt(8)" ::: "memory");
            else                      asm volatile("s_waitcnt vmcnt(6)" ::: "memory");
        } else {
            asm volatile("s_waitcnt vmcnt(0)" ::: "memory");
        }
        __builtin_amdgcn_s_barrier();

        const u16* sAc = smem + cur * (AE + BE);
        const u16* sBc = sAc + AE;

        half8 Ar[4][2], Bq0[NF2][2], Bq1[NF2][2];

        auto ldA = [&](int mh) {
#pragma unroll
            for (int fi = 0; fi < 4; ++fi) {
                const int r = wr * 128 + (mh * 4 + fi) * 16 + lr;
                Ar[fi][0] = *(const half8*)&sAc[r * 64 + ch0];
                Ar[fi][1] = *(const half8*)&sAc[r * 64 + ch1];
            }
        };
        auto ldB = [&](half8 (&Br)[NF2][2], int nh) {
#pragma unroll
            for (int nj = 0; nj < NF2; ++nj) {
                const int r = wc * WN + (nh * NF2 + nj) * 16 + lr;
                Br[nj][0] = *(const half8*)&sBc[r * 64 + ch0];
                Br[nj][1] = *(const half8*)&sBc[r * 64 + ch1];
            }
        };
        auto quad = [&](half8 (&Br)[NF2][2], int mh, int nh) {
            __builtin_amdgcn_s_setprio(1);
#pragma unroll
            for (int fi = 0; fi < 4; ++fi)
#pragma unroll
                for (int nj = 0; nj < NF2; ++nj)
#pragma unroll
                    for (int ks = 0; ks < 2; ++ks)
                        acc[mh * 4 + fi][nh * NF2 + nj] =
                            __builtin_amdgcn_mfma_f32_16x16x32_f16(
                                Ar[fi][ks], Br[nj][ks], acc[mh * 4 + fi][nh * NF2 + nj], 0, 0, 0);
            __builtin_amdgcn_s_setprio(0);
        };

        ldA(0); ldB(Bq0, 0); quad(Bq0, 0, 0);
        ldB(Bq1, 1);         quad(Bq1, 0, 1);
        ldA(1);              quad(Bq1, 1, 1);
                             quad(Bq0, 1, 0);

        __builtin_amdgcn_s_barrier();
        cur ^= 1;
    }

    // epilogue: C/D mapping col = lane&15, row = (lane>>4)*4 + reg
#pragma unroll
    for (int f = 0; f < 8; ++f) {
        const long rb = row0 + wr * 128 + f * 16 + lh * 4;
#pragma unroll
        for (int n = 0; n < NF; ++n) {
            const long c = col0 + wc * WN + n * 16 + lr;
#pragma unroll
            for (int r = 0; r < 4; ++r)
                storeC(C, (size_t)(rb + r) * ldc + c, acc[f][n][r]);
        }
    }
}

// ---------- row softmax WITH mask: scores fp32 [8192][2048] (+mask) -> P f16 ----------
__global__ __launch_bounds__(256) void softmax_kernel(
    const float* __restrict__ S, const unsigned char* __restrict__ mask8,
    const int* __restrict__ mask32, const int* __restrict__ mflagp,
    u16* __restrict__ P)
{
    const long row = blockIdx.x;
    const int t = threadIdx.x;
    const int lane = t & 63, wid = t >> 6;
    const int mf = *mflagp;   // 1 -> uint8 bool, 0 -> int32
    const float* src = S + row * 2048;
    float4 a = *(const float4*)(src + t * 8);
    float4 b = *(const float4*)(src + t * 8 + 4);
    float v[8] = {a.x, a.y, a.z, a.w, b.x, b.y, b.z, b.w};

    // coalesced mask read + apply
    const float NINF = -__builtin_inff();
    if (mf) {
        const unsigned long long mm =
            *(const unsigned long long*)(mask8 + row * 2048 + t * 8);
#pragma unroll
        for (int i = 0; i < 8; ++i)
            if ((mm >> (8 * i)) & 0xffULL) v[i] = NINF;
    } else {
        const int4 ma = *(const int4*)(mask32 + row * 2048 + t * 8);
        const int4 mb = *(const int4*)(mask32 + row * 2048 + t * 8 + 4);
        if (ma.x) v[0] = NINF; if (ma.y) v[1] = NINF;
        if (ma.z) v[2] = NINF; if (ma.w) v[3] = NINF;
        if (mb.x) v[4] = NINF; if (mb.y) v[5] = NINF;
        if (mb.z) v[6] = NINF; if (mb.w) v[7] = NINF;
    }

    float m = v[0];
#pragma unroll
    for (int i = 1; i < 8; ++i) m = fmaxf(m, v[i]);
#pragma unroll
    for (int off = 32; off; off >>= 1) m = fmaxf(m, __shfl_xor(m, off));
    __shared__ float redm[4];
    __shared__ float reds[4];
    if (lane == 0) redm[wid] = m;
    __syncthreads();
    m = fmaxf(fmaxf(redm[0], redm[1]), fmaxf(redm[2], redm[3]));

    float e[8], s = 0.f;
#pragma unroll
    for (int i = 0; i < 8; ++i) { e[i] = __expf(v[i] - m); s += e[i]; }
#pragma unroll
    for (int off = 32; off; off >>= 1) s += __shfl_xor(s, off);
    if (lane == 0) reds[wid] = s;
    __syncthreads();
    s = (reds[0] + reds[1]) + (reds[2] + reds[3]);
    const float inv = 1.0f / s;

    short8 o;
#pragma unroll
    for (int i = 0; i < 8; ++i) o[i] = (short)f2h(e[i] * inv);
    *(short8*)(P + row * 2048 + t * 8) = o;
}

// ---------- launch ----------
extern "C" void kernel_launch(void* const* d_in, const int* in_sizes, int n_in,
                              void* d_out, int out_size, void* d_ws, size_t ws_size,
                              hipStream_t stream)
{
    const float* dec  = (const float*)d_in[0];          // [16][512][1024]
    const float* enc  = (const float*)d_in[1];          // [16][2048][1024]
    const void*  mask = (const void*)d_in[2];           // [16][512][2048] bool or int32
    const float* W    = (const float*)d_in[3];          // [1024][2048]
    float* out        = (float*)d_out;                  // [16][512][1024]

    // workspace carve (total 289,411,072 B)
    char* ws = (char*)d_ws;
    u16*   dec16  = (u16*)ws;                 ws += 16777216;   // 8192x1024 f16
    u16*   enc16  = (u16*)ws;                 ws += 67108864;   // 16x2048x1024 f16
    u16*   encT   = (u16*)ws;                 ws += 67108864;   // 16x1024x2048 f16
    u16*   W16    = (u16*)ws;                 ws += 4194304;    // 1024x2048 f16
    float* scores = (float*)ws;               ws += 67108864;   // 8192x2048 fp32
    u16*   P      = (u16*)ws;                 ws += 33554432;   // 8192x2048 f16
    u16*   cat    = (u16*)ws;                 ws += 33554432;   // 8192x2048 f16
    int*   mflag  = (int*)ws;                 ws += 4096;       // mask dtype flag
    if (ws_size < (size_t)289411072) return;

    // 0) detect mask dtype (needed by softmax)
    detect_mask_kernel<<<1, 256, 0, stream>>>((const unsigned char*)mask, mflag);

    // 1) casts
    cast_f16_kernel<<<8192, 256, 0, stream>>>(dec, dec16, cat + 1024, 8388608L);
    cast_enc_kernel<<<dim3(32, 16, 16), 256, 0, stream>>>(enc, enc16, encT);
    cast_f16_kernel<<<2048, 256, 0, stream>>>(W, W16, nullptr, 2097152L);

    // 2) scores = dec @ enc^T (no mask)  (256x256 tiles, 16b x 2 x 8 = 256 blocks)
    gemm8_kernel<256, float><<<256, 512, 0, stream>>>(
        dec16, 1024, 512L * 1024,
        enc16, 1024, 2048L * 1024,
        scores, 2048, 512L * 2048,
        1024, 2, 8);

    // 3) mask + softmax rows -> P (f16)
    softmax_kernel<<<8192, 256, 0, stream>>>(
        scores, (const unsigned char*)mask, (const int*)mask, mflag, P);

    // 4) context = P @ encT^T -> cat left half  (256x128 tiles, 256 blocks)
    gemm8_kernel<128, u16><<<256, 512, 0, stream>>>(
        P, 2048, 512L * 2048,
        encT, 2048, 1024L * 2048,
        cat, 2048, 512L * 2048,
        2048, 2, 8);

    // 5) out = cat @ W^T -> fp32  (256x128 tiles, 32mt x 8nt = 256 blocks, batch-free)
    gemm8_kernel<128, float><<<256, 512, 0, stream>>>(
        cat, 2048, 0,
        W16, 2048, 0,
        out, 1024, 0,
        2048, 32, 8);
}